// Round 10
// baseline (40.677 us; speedup 1.0000x reference)
//
#include <hip/hip_runtime.h>
#include <cstdint>

#define BTOT 4096
#define NBLK 2048   // 2 batches per 64-lane wave; 8 blocks/CU = 2 waves/SIMD, no tail
#define T0   936    // simulate only t in [936, 1000): earlier steps are warmup;
                    // s2 weight 2^-(1001-t) is sub-threshold for t<~985
#define NT   64
#define GSTR 904    // per-group LDS stride (dwords): 904 mod 32 = 8 -> the two
                    // groups' b128 x-reads land in disjoint bank quads

__device__ __forceinline__ void gload_lds16(const void* g, void* l) {
  __builtin_amdgcn_global_load_lds(
      (const __attribute__((address_space(1))) void*)g,
      (__attribute__((address_space(3))) void*)l, 16, 0, 0);
}

// One wave per block. Lanes 0..39 = 2 batch groups x 20 neurons; lanes 40..63 idle.
// LDS: sm[0..2047]     x staging (one shot): group g at g*904, row l at +l*64
//      sm[2048..4607]  LUT[4][32][20], nibble-sums of W2 columns, pre-scaled 0.5
//      sm[4608..4647]  epilogue exchange
__global__ __launch_bounds__(64)
void snn_kernel(const float* __restrict__ x, const float* __restrict__ W1,
                const float* __restrict__ W2, const float* __restrict__ W3,
                float* __restrict__ out) {
  __shared__ __align__(16) float sm[4648];
  float* lutf = sm + 2048;
  const int lane = threadIdx.x;
  const int bid  = blockIdx.x;

  // ---- issue x staging FIRST; latency hides under the LUT build ----
  // Dest dword d = it*256 + lane*4 (linear, wave-uniform base + lane*16B).
  // d < 1808 used: gg = d/904, r = d%904, l = r>>6 (clamp 13), tc = r&63.
  // d >= 1808 are pad slots (clamped source, contents unused).
  #pragma unroll
  for (int it = 0; it < 8; ++it) {
    int d  = it * 256 + lane * 4;
    int gg = d >= GSTR ? 1 : 0;
    int r  = d - gg * GSTR;
    int l  = r >> 6;
    if (l > 13) l = 13;
    int tc = r & 63;
    const long bb = (long)bid * 2 + gg;
    const float* src = x + (bb * 14 + l) * 1000 + T0 + tc;
    gload_lds16(src, sm + it * 256);
  }

  // ---- build LUT: lutf[q*640 + m*20 + i] = 0.5 * sum_{k in m} W2[i][5q+k] ----
  for (int idx = lane; idx < 2560; idx += 64) {
    int q   = idx / 640;
    int rem = idx - q * 640;
    int m   = rem / 20;
    int i   = rem - m * 20;
    float s = 0.f;
    #pragma unroll
    for (int k = 0; k < 5; ++k)
      if (m & (1 << k)) s += W2[i * 20 + q * 5 + k];
    lutf[idx] = 0.5f * s;
  }

  const int  g1     = lane / 20;            // 0..3
  const int  g      = g1 < 2 ? g1 : 1;      // clamp idle lanes onto group 1
  const int  i      = lane - g * 20;
  const int  i19    = i < 20 ? i : 19;
  const bool active = (lane < 40);
  const long b      = (long)bid * 2 + g;    // always < 4096 (2048*2 exact)

  // W1 row, pre-scaled by 0.5 (folds the /tau).
  float w1r[14];
  #pragma unroll
  for (int l = 0; l < 14; ++l) w1r[l] = 0.5f * W1[i19 * 14 + l];

  float v1 = 0.f, v2 = 0.f, aacc = 0.f;
  const unsigned sh = 20u * (unsigned)g;

  __syncthreads();  // drains vmcnt (staging) + lgkmcnt (LUT writes)

  const float* xg = sm + g * GSTR;

  for (int tc4 = 0; tc4 < NT / 4; ++tc4) {
    float4 xr[14];
    #pragma unroll
    for (int l = 0; l < 14; ++l)
      xr[l] = *(const float4*)(xg + l * 64 + tc4 * 4);  // b128 broadcast, conflict-free

    // ---- Phase A: h1 + v1 chain + ballots ----
    float ha = 0.f, hb = 0.f, hc = 0.f, hd = 0.f;
    #pragma unroll
    for (int l = 0; l < 14; ++l) {
      const float w = w1r[l];
      ha = fmaf(w, xr[l].x, ha);
      hb = fmaf(w, xr[l].y, hb);
      hc = fmaf(w, xr[l].z, hc);
      hd = fmaf(w, xr[l].w, hd);
    }
    float h1v[4] = {ha, hb, hc, hd};

    unsigned mk[4];
    #pragma unroll
    for (int dt = 0; dt < 4; ++dt) {
      v1 = fmaf(v1, 0.5f, h1v[dt]);   // v' = v/2 + h/2 (W1 pre-scaled)
      const bool sp1 = (v1 >= 5.0f);
      v1 = sp1 ? 0.f : v1;
      mk[dt] = (unsigned)(__ballot(sp1) >> sh);  // bits >19 junk; bfe masks
    }

    // ---- Phase B: all 16 LUT loads issued back-to-back ----
    float hq[16];
    #pragma unroll
    for (int dt = 0; dt < 4; ++dt) {
      #pragma unroll
      for (int q = 0; q < 4; ++q)
        hq[dt * 4 + q] = lutf[q * 640 + ((mk[dt] >> (5 * q)) & 31u) * 20 + i19];
    }

    // ---- Phase C: v2 / aacc chain ----
    #pragma unroll
    for (int dt = 0; dt < 4; ++dt) {
      const float h2 = (hq[dt * 4 + 0] + hq[dt * 4 + 1]) +
                       (hq[dt * 4 + 2] + hq[dt * 4 + 3]);  // already *0.5
      v2 = fmaf(v2, 0.5f, h2);
      const bool sp2 = (v2 >= 5.0f);
      v2 = sp2 ? 0.f : v2;
      aacc = fmaf(aacc, 0.5f, sp2 ? 0.5f : 0.f);
    }
  }

  // ---- Epilogue: out[b][k] = exp( sum_j W3[k][j] * a[j] ), float4 W3 reads ----
  __syncthreads();
  if (active) sm[4608 + g * 20 + i] = aacc;
  __syncthreads();
  if (active) {
    float4 ar4[5];
    #pragma unroll
    for (int p = 0; p < 5; ++p)
      ar4[p] = *(const float4*)(sm + 4608 + g * 20 + p * 4);
    for (int q = 0; q < 25; ++q) {
      const int k = i + 20 * q;
      const float4* w3v = (const float4*)(W3 + k * 20);
      float acc = 0.f;
      #pragma unroll
      for (int p = 0; p < 5; ++p) {
        const float4 w4 = w3v[p];
        acc = fmaf(w4.x, ar4[p].x, acc);
        acc = fmaf(w4.y, ar4[p].y, acc);
        acc = fmaf(w4.z, ar4[p].z, acc);
        acc = fmaf(w4.w, ar4[p].w, acc);
      }
      out[b * 500 + k] = expf(acc);
    }
  }
}

extern "C" void kernel_launch(void* const* d_in, const int* in_sizes, int n_in,
                              void* d_out, int out_size, void* d_ws, size_t ws_size,
                              hipStream_t stream) {
  const float* x  = (const float*)d_in[0];
  const float* W1 = (const float*)d_in[1];
  const float* W2 = (const float*)d_in[2];
  const float* W3 = (const float*)d_in[3];
  float* out = (float*)d_out;
  snn_kernel<<<dim3(NBLK), dim3(64), 0, stream>>>(x, W1, W2, W3, out);
}

// Round 11
// 21.482 us; speedup vs baseline: 1.8935x; 1.8935x over previous
//
#include <hip/hip_runtime.h>
#include <cstdint>

#define BTOT  4096
#define NBLK  1366   // 3 batches per wave; 5.34 blocks/CU
#define T0    936    // simulate t in [936,1000): earlier steps are warmup (round 8/9)
#define NT    64
#define GSTR  904    // x staging group stride (dwords)
#define H1STR 68     // h1 row stride (dwords): %4==0 (b128 align), mod32=4 (bank spread)
#define LUTB  4080   // LUT base (dwords) = 60*H1STR
#define SMTOT 6640   // 4080 (h1/x-stage) + 2560 (LUT); exchange reuses sm[0:64)

typedef float f32x4 __attribute__((ext_vector_type(4)));

__device__ __forceinline__ void gload_lds16(const void* g, void* l) {
  __builtin_amdgcn_global_load_lds(
      (const __attribute__((address_space(1))) void*)g,
      (__attribute__((address_space(3))) void*)l, 16, 0, 0);
}

// One wave per block. Main mapping: lanes 0..59 = 3 groups x 20 neurons.
// Phase-1 mapping: lanes 0..47 = 3 groups x 16 t-blocks (4 steps each).
// LDS: sm[0:4080)  h1[60][68]  (x staged transiently into [0:2816) first)
//      sm[4080:6640) LUT[4][32][20] (built VMEM-free, bit-identical entries)
//      sm[0:64)    epilogue exchange (h1 dead by then)
__global__ __launch_bounds__(64)
void snn_kernel(const float* __restrict__ x, const float* __restrict__ W1,
                const float* __restrict__ W2, const float* __restrict__ W3,
                float* __restrict__ out) {
  __shared__ __align__(16) float sm[SMTOT];
  float* lutf = sm + LUTB;
  const int lane = threadIdx.x;
  const int bid  = blockIdx.x;

  // ---- stage x first: 11 granules, latency hides under LUT build ----
  // dest dword d = it*256 + lane*4; d -> (gg = d/904 clamp 2, l = (d%904)>>6
  // clamp 13, tc = d%64); pad slots read a clamped valid address.
  #pragma unroll
  for (int it = 0; it < 11; ++it) {
    int d  = it * 256 + lane * 4;
    int gg = d / GSTR; if (gg > 2) gg = 2;
    int r  = d - gg * GSTR;
    int l  = r >> 6;  if (l > 13) l = 13;
    int tc = r & 63;
    long bb = (long)bid * 3 + gg;
    if (bb > BTOT - 1) bb = BTOT - 1;
    gload_lds16(x + (bb * 14 + l) * 1000 + T0 + tc, sm + it * 256);
  }

  // ---- LUT build, VMEM-light: lane (bi, half) owns neuron bi, q = 2*half+qr.
  // Entry arithmetic identical to prior rounds: ascending-k adds, then *0.5f.
  if (lane < 40) {
    const int bi   = lane % 20;
    const int half = lane / 20;
    float w2r[10];
    const float* wsrc = W2 + bi * 20 + half * 10;
    #pragma unroll
    for (int k = 0; k < 5; ++k) {
      float2 t = *(const float2*)(wsrc + 2 * k);
      w2r[2 * k] = t.x; w2r[2 * k + 1] = t.y;
    }
    float* dst = lutf + half * 1280 + bi;
    #pragma unroll
    for (int qr = 0; qr < 2; ++qr) {
      #pragma unroll
      for (int m = 0; m < 32; ++m) {
        float s = 0.f;
        if (m & 1)  s += w2r[qr * 5 + 0];
        if (m & 2)  s += w2r[qr * 5 + 1];
        if (m & 4)  s += w2r[qr * 5 + 2];
        if (m & 8)  s += w2r[qr * 5 + 3];
        if (m & 16) s += w2r[qr * 5 + 4];
        dst[qr * 640 + m * 20] = 0.5f * s;
      }
    }
  }

  __syncthreads();  // x staged (vmcnt drained) + LUT written

  // ---- phase-1: h1[g][i][t] = sum_l W1[i][l]*(0.5*x[g][l][t]) ----
  // fmaf(W1, 0.5x) == fmaf(0.5*W1, x) bit-exactly (x0.5 is exponent-only),
  // same ascending-l fma order as all prior rounds.
  {
    const int pg = (lane >> 4) < 3 ? (lane >> 4) : 2;  // lanes 48..63 dup reads
    const int tb = lane & 15;
    f32x4 xl[14];
    const float* xs = sm + pg * GSTR + tb * 4;
    #pragma unroll
    for (int l = 0; l < 14; ++l) xl[l] = *(const f32x4*)(xs + l * 64);
    #pragma unroll
    for (int l = 0; l < 14; ++l) xl[l] = xl[l] * 0.5f;  // exact

    __syncthreads();  // all x reads in regs before h1 overwrites the region

    if (lane < 48) {
      float* hdst = sm + pg * 20 * H1STR + tb * 4;
      #pragma unroll
      for (int ii = 0; ii < 20; ++ii) {
        f32x4 acc = 0.f;
        #pragma unroll
        for (int l = 0; l < 14; ++l) {
          const float w = W1[ii * 14 + l];   // wave-uniform -> s_load
          const f32x4 wv = w;
          acc = __builtin_elementwise_fma(wv, xl[l], acc);  // v_pk_fma_f32
        }
        *(f32x4*)(hdst + ii * H1STR) = acc;
      }
    }
  }

  const int  g3     = lane / 20;
  const int  g      = g3 < 3 ? g3 : 2;
  const int  i      = lane - g * 20;
  const int  i19    = i < 20 ? i : 19;
  const bool active = (g3 < 3);
  const long b      = (long)bid * 3 + g;
  const bool bvalid = (b < BTOT);

  float v1 = 0.f, v2 = 0.f, aacc = 0.f;
  const unsigned sh = 20u * (unsigned)g;

  __syncthreads();  // h1 visible

  const float* h1p = sm + (g * 20 + i19) * H1STR;

  #pragma unroll 2
  for (int tc4 = 0; tc4 < NT / 4; ++tc4) {
    const f32x4 h1v = *(const f32x4*)(h1p + tc4 * 4);  // one b128 per 4 steps

    // ---- Phase A: v1 chain + ballots ----
    unsigned mk[4];
    #pragma unroll
    for (int dt = 0; dt < 4; ++dt) {
      v1 = fmaf(v1, 0.5f, h1v[dt]);   // v' = v/2 + h/2 (h pre-scaled)
      const bool sp1 = (v1 >= 5.0f);
      v1 = sp1 ? 0.f : v1;
      mk[dt] = (unsigned)(__ballot(sp1) >> sh);  // bits >19 junk; bfe masks
    }

    // ---- Phase B: all 16 LUT loads issued back-to-back ----
    float hq[16];
    #pragma unroll
    for (int dt = 0; dt < 4; ++dt) {
      #pragma unroll
      for (int q = 0; q < 4; ++q)
        hq[dt * 4 + q] = lutf[q * 640 + ((mk[dt] >> (5 * q)) & 31u) * 20 + i19];
    }

    // ---- Phase C: v2 / aacc chain ----
    #pragma unroll
    for (int dt = 0; dt < 4; ++dt) {
      const float h2 = (hq[dt * 4 + 0] + hq[dt * 4 + 1]) +
                       (hq[dt * 4 + 2] + hq[dt * 4 + 3]);  // already *0.5
      v2 = fmaf(v2, 0.5f, h2);
      const bool sp2 = (v2 >= 5.0f);
      v2 = sp2 ? 0.f : v2;
      aacc = fmaf(aacc, 0.5f, sp2 ? 0.5f : 0.f);
    }
  }

  // ---- Epilogue: out[b][k] = exp( sum_j W3[k][j] * a[j] ) ----
  __syncthreads();
  if (active) sm[g * 20 + i] = aacc;   // exchange reuses h1 region (dead)
  __syncthreads();
  if (active && bvalid) {
    float4 ar4[5];
    #pragma unroll
    for (int p = 0; p < 5; ++p)
      ar4[p] = *(const float4*)(sm + g * 20 + p * 4);
    for (int q = 0; q < 25; ++q) {
      const int k = i + 20 * q;
      const float4* w3v = (const float4*)(W3 + k * 20);
      float acc = 0.f;
      #pragma unroll
      for (int p = 0; p < 5; ++p) {
        const float4 w4 = w3v[p];
        acc = fmaf(w4.x, ar4[p].x, acc);
        acc = fmaf(w4.y, ar4[p].y, acc);
        acc = fmaf(w4.z, ar4[p].z, acc);
        acc = fmaf(w4.w, ar4[p].w, acc);
      }
      out[b * 500 + k] = expf(acc);
    }
  }
}

extern "C" void kernel_launch(void* const* d_in, const int* in_sizes, int n_in,
                              void* d_out, int out_size, void* d_ws, size_t ws_size,
                              hipStream_t stream) {
  const float* x  = (const float*)d_in[0];
  const float* W1 = (const float*)d_in[1];
  const float* W2 = (const float*)d_in[2];
  const float* W3 = (const float*)d_in[3];
  float* out = (float*)d_out;
  snn_kernel<<<dim3(NBLK), dim3(64), 0, stream>>>(x, W1, W2, W3, out);
}

// Round 12
// 20.720 us; speedup vs baseline: 1.9632x; 1.0368x over previous
//
#include <hip/hip_runtime.h>
#include <cstdint>

#define BTOT  4096
#define NBLK  1366   // 3 batches per wave; 5.34 blocks/CU
#define T0    936    // simulate t in [936,1000): earlier steps are warmup (rounds 8/9)
#define NT    64
#define H1STR 68     // h1 row stride (dwords): %4==0 (b128 align), mod32=4 (bank spread)
#define LUTB  4080   // LUT base (dwords) = 60*H1STR
#define SMTOT 6640   // 4080 (h1) + 2560 (LUT); epilogue exchange reuses sm[0:64)

typedef float f32x4 __attribute__((ext_vector_type(4)));

// One wave per block. Main mapping: lanes 0..59 = 3 groups x 20 neurons.
// Phase-1 mapping: lanes 0..47 = 3 groups x 16 t-blocks (4 steps each); x is read
// straight from global (coalesced 256B/row per group) into 14 float4 regs - no LDS
// staging, no gload_lds, one less barrier. LUT[4][32][20] built VMEM-light from W2
// with the 0.5 prescale folded into the register load (bit-identical entries).
__global__ __launch_bounds__(64)
void snn_kernel(const float* __restrict__ x, const float* __restrict__ W1,
                const float* __restrict__ W2, const float* __restrict__ W3,
                float* __restrict__ out) {
  __shared__ __align__(16) float sm[SMTOT];
  float* lutf = sm + LUTB;
  const int lane = threadIdx.x;
  const int bid  = blockIdx.x;

  // ---- phase-1 x loads: issued FIRST, consumed after the LUT build ----
  const int pg = (lane >> 4) < 3 ? (lane >> 4) : 2;  // lanes 48..63 dup group 2
  const int tb = lane & 15;
  long bbp = (long)bid * 3 + pg;
  if (bbp > BTOT - 1) bbp = BTOT - 1;
  const float* xbase = x + bbp * 14000 + T0;
  f32x4 xl[14];
  #pragma unroll
  for (int l = 0; l < 14; ++l)
    xl[l] = *(const f32x4*)(xbase + l * 1000 + tb * 4);  // coalesced b128

  // ---- LUT build (lanes 0..39): lane (bi, half) owns neuron bi, q = 2*half+qr.
  // w2r prescaled by 0.5 (exact); ascending-k conditional adds -> entries
  // bit-identical to all prior rounds (0.5*sum == sum of 0.5-terms exactly).
  if (lane < 40) {
    const int bi   = lane % 20;
    const int half = lane / 20;
    float w2r[10];
    const float* wsrc = W2 + bi * 20 + half * 10;
    #pragma unroll
    for (int k = 0; k < 5; ++k) {
      float2 t = *(const float2*)(wsrc + 2 * k);
      w2r[2 * k]     = 0.5f * t.x;
      w2r[2 * k + 1] = 0.5f * t.y;
    }
    float* dst = lutf + half * 1280 + bi;
    #pragma unroll
    for (int qr = 0; qr < 2; ++qr) {
      #pragma unroll
      for (int m = 0; m < 32; ++m) {
        float s = 0.f;
        if (m & 1)  s += w2r[qr * 5 + 0];
        if (m & 2)  s += w2r[qr * 5 + 1];
        if (m & 4)  s += w2r[qr * 5 + 2];
        if (m & 8)  s += w2r[qr * 5 + 3];
        if (m & 16) s += w2r[qr * 5 + 4];
        dst[qr * 640 + m * 20] = s;
      }
    }
  }

  // ---- phase-1: h1[g][i][t] = sum_l W1[i][l]*(0.5*x[g][l][t]) ----
  // fmaf(W1, 0.5x) == fmaf(0.5W1, x) bit-exactly; ascending-l order unchanged.
  #pragma unroll
  for (int l = 0; l < 14; ++l) xl[l] = xl[l] * 0.5f;    // exact (exponent only)

  if (lane < 48) {
    float* hdst = sm + pg * 20 * H1STR + tb * 4;
    #pragma unroll
    for (int ii = 0; ii < 20; ++ii) {
      f32x4 acc = 0.f;
      #pragma unroll
      for (int l = 0; l < 14; ++l) {
        const float w = W1[ii * 14 + l];   // wave-uniform -> s_load
        const f32x4 wv = w;
        acc = __builtin_elementwise_fma(wv, xl[l], acc);  // v_pk_fma_f32
      }
      *(f32x4*)(hdst + ii * H1STR) = acc;
    }
  }

  const int  g3     = lane / 20;
  const int  g      = g3 < 3 ? g3 : 2;
  const int  i      = lane - g * 20;
  const int  i19    = i < 20 ? i : 19;
  const bool active = (g3 < 3);
  const long b      = (long)bid * 3 + g;
  const bool bvalid = (b < BTOT);

  float v1 = 0.f, v2 = 0.f, aacc = 0.f;
  const unsigned sh = 20u * (unsigned)g;

  __syncthreads();  // h1 + LUT visible

  const float* h1p = sm + (g * 20 + i19) * H1STR;

  #pragma unroll 4
  for (int tc4 = 0; tc4 < NT / 4; ++tc4) {
    const f32x4 h1v = *(const f32x4*)(h1p + tc4 * 4);  // one b128 per 4 steps

    // ---- Phase A: v1 chain + ballots ----
    unsigned mk[4];
    #pragma unroll
    for (int dt = 0; dt < 4; ++dt) {
      v1 = fmaf(v1, 0.5f, h1v[dt]);   // v' = v/2 + h/2 (h pre-scaled)
      const bool sp1 = (v1 >= 5.0f);
      v1 = sp1 ? 0.f : v1;
      mk[dt] = (unsigned)(__ballot(sp1) >> sh);  // bits >19 junk; bfe masks
    }

    // ---- Phase B: all 16 LUT loads issued back-to-back ----
    float hq[16];
    #pragma unroll
    for (int dt = 0; dt < 4; ++dt) {
      #pragma unroll
      for (int q = 0; q < 4; ++q)
        hq[dt * 4 + q] = lutf[q * 640 + ((mk[dt] >> (5 * q)) & 31u) * 20 + i19];
    }

    // ---- Phase C: v2 / aacc chain ----
    #pragma unroll
    for (int dt = 0; dt < 4; ++dt) {
      const float h2 = (hq[dt * 4 + 0] + hq[dt * 4 + 1]) +
                       (hq[dt * 4 + 2] + hq[dt * 4 + 3]);  // already *0.5
      v2 = fmaf(v2, 0.5f, h2);
      const bool sp2 = (v2 >= 5.0f);
      v2 = sp2 ? 0.f : v2;
      aacc = fmaf(aacc, 0.5f, sp2 ? 0.5f : 0.f);
    }
  }

  // ---- Epilogue: out[b][k] = exp( sum_j W3[k][j] * a[j] ) ----
  __syncthreads();
  if (active) sm[g * 20 + i] = aacc;   // exchange reuses h1 region (dead)
  __syncthreads();
  if (active && bvalid) {
    float4 ar4[5];
    #pragma unroll
    for (int p = 0; p < 5; ++p)
      ar4[p] = *(const float4*)(sm + g * 20 + p * 4);
    for (int q = 0; q < 25; ++q) {
      const int k = i + 20 * q;
      const float4* w3v = (const float4*)(W3 + k * 20);
      float acc = 0.f;
      #pragma unroll
      for (int p = 0; p < 5; ++p) {
        const float4 w4 = w3v[p];
        acc = fmaf(w4.x, ar4[p].x, acc);
        acc = fmaf(w4.y, ar4[p].y, acc);
        acc = fmaf(w4.z, ar4[p].z, acc);
        acc = fmaf(w4.w, ar4[p].w, acc);
      }
      out[b * 500 + k] = __expf(acc);
    }
  }
}

extern "C" void kernel_launch(void* const* d_in, const int* in_sizes, int n_in,
                              void* d_out, int out_size, void* d_ws, size_t ws_size,
                              hipStream_t stream) {
  const float* x  = (const float*)d_in[0];
  const float* W1 = (const float*)d_in[1];
  const float* W2 = (const float*)d_in[2];
  const float* W3 = (const float*)d_in[3];
  float* out = (float*)d_out;
  snn_kernel<<<dim3(NBLK), dim3(64), 0, stream>>>(x, W1, W2, W3, out);
}